// Round 13
// baseline (971.804 us; speedup 1.0000x reference)
//
#include <hip/hip_runtime.h>
#include <hip/hip_fp16.h>
#include <math.h>

#define N_NODES 100000
#define N_EDGES 3200000
#define INC 128
#define HID 64

constexpr int BLK = 256;
constexpr int NBLK_N = (N_NODES + BLK - 1) / BLK;   // 391

constexpr int NBUCK = (N_NODES + 127) / 128;        // 782 buckets of 128 dsts
constexpr int CAP = 4608;                           // staging cap: mean 4096 + 8 sigma
constexpr int CAPP = 6528;                          // csr region cap: CAP + 128*15 pad headroom
constexpr int CHUNK = 8192;
constexpr int NCHUNK = (N_EDGES + CHUNK - 1) / CHUNK; // 391

typedef _Float16 half2v __attribute__((ext_vector_type(2)));
__device__ __forceinline__ float fdot2(unsigned a, unsigned b, float c) {
    return __builtin_amdgcn_fdot2(__builtin_bit_cast(half2v, a),
                                  __builtin_bit_cast(half2v, b), c, false);
}

__global__ void init_k(int* __restrict__ cursor, float* __restrict__ stats) {
    int i = blockIdx.x * blockDim.x + threadIdx.x;
    if (i < NBUCK) cursor[i] = i * CAP;
    else if (i < NBUCK + 384) stats[i - NBUCK] = 0.f;
}

// One block per 8192-edge chunk: bucket-sort in LDS, one global atomic per
// non-empty bucket, coalesced SoA flush (4B+2B).
__global__ __launch_bounds__(BLK) void sort_scatter(
    const int* __restrict__ src, const int* __restrict__ dst,
    const float* __restrict__ ew, int* __restrict__ gcur,
    unsigned* __restrict__ ebuf_lo, unsigned short* __restrict__ ebuf_ew)
{
    __shared__ unsigned s_lo[CHUNK];
    __shared__ unsigned short s_ew[CHUNK];
    __shared__ int s_cnt[NBUCK];
    __shared__ int s_base[NBUCK];
    int tid = threadIdx.x;
    int c0 = blockIdx.x * CHUNK;
    int T = min(CHUNK, N_EDGES - c0);
    if (T <= 0) return;
    for (int i = tid; i < NBUCK; i += BLK) s_cnt[i] = 0;
    __syncthreads();
    for (int i = tid; i < T; i += BLK)
        atomicAdd(&s_cnt[dst[c0 + i] >> 7], 1);
    __syncthreads();
    int* a = (int*)s_lo;
    int* b2 = a + 1024;
    for (int i = tid; i < NBUCK; i += BLK) a[i] = s_cnt[i];
    __syncthreads();
    for (int d = 1; d < NBUCK; d <<= 1) {
        for (int i = tid; i < NBUCK; i += BLK) b2[i] = a[i] + (i >= d ? a[i - d] : 0);
        __syncthreads();
        int* tmp = a; a = b2; b2 = tmp;
    }
    for (int b = tid; b < NBUCK; b += BLK) {
        int cnt = s_cnt[b];
        int pex = a[b] - cnt;
        int gb = cnt ? (atomicAdd(&gcur[b], cnt) - b * CAP) : 0;
        s_base[b] = gb - pex;
        s_cnt[b] = pex;
    }
    __syncthreads();
    for (int i = tid; i < T; i += BLK) {
        int d = dst[c0 + i];
        int s = src[c0 + i];
        float w = ew[c0 + i];
        int b = d >> 7;
        int r = atomicAdd(&s_cnt[b], 1);
        s_lo[r] = (unsigned)s | ((unsigned)(d & 127) << 17);
        s_ew[r] = __half_as_ushort(__float2half_rn(w));
    }
    __syncthreads();
    for (int j = tid; j < T; j += BLK) {
        int lo = 0, hi = NBUCK - 1;
        while (lo < hi) { int mid = (lo + hi) >> 1; if (s_cnt[mid] > j) hi = mid; else lo = mid + 1; }
        int b = lo;
        int rel = s_base[b] + j;
        if (rel < CAP) {
            ebuf_lo[(size_t)b * CAP + rel] = s_lo[j];
            ebuf_ew[(size_t)b * CAP + rel] = s_ew[j];
        }
    }
}

// One block per bucket: per-dst counts, padded (x16) scan, dst-sorted rewrite into
// fixed region [b*CAPP...]. Entry 4B: src(17b) | fp16-ew-no-sign(15b).
__global__ __launch_bounds__(BLK) void build_csr(
    const unsigned* __restrict__ ebuf_lo, const unsigned short* __restrict__ ebuf_ew,
    const int* __restrict__ gcur, int* __restrict__ offs2,
    int* __restrict__ cntg, unsigned* __restrict__ csr)
{
    __shared__ int cntl[128];
    __shared__ int scp[128];
    __shared__ int pos[128];
    int b = blockIdx.x, tid = threadIdx.x;
    if (tid < 128) cntl[tid] = 0;
    __syncthreads();
    int cn = min(gcur[b] - b * CAP, CAP);
    const unsigned* lop = ebuf_lo + (size_t)b * CAP;
    const unsigned short* ewp = ebuf_ew + (size_t)b * CAP;
    for (int i = tid; i < cn; i += BLK)
        atomicAdd(&cntl[lop[i] >> 17], 1);
    __syncthreads();
    if (tid < 128) scp[tid] = (cntl[tid] + 15) & ~15;
    __syncthreads();
    for (int d = 1; d < 128; d <<= 1) {
        int t = (tid < 128 && tid >= d) ? scp[tid - d] : 0;
        __syncthreads();
        if (tid < 128) scp[tid] += t;   // inclusive scan of padded counts
        __syncthreads();
    }
    int base = b * CAPP;
    int node0 = b * 128;
    if (tid < 128) {
        int cnt = cntl[tid];
        int cp = (cnt + 15) & ~15;
        int excl = scp[tid] - cp;
        pos[tid] = excl;
        if (node0 + tid < N_NODES) {
            offs2[node0 + tid] = base + excl;
            cntg[node0 + tid] = cp;        // padded count
        }
        for (int q = cnt; q < cp; ++q) csr[base + excl + q] = 0u;  // w=0 pad
    }
    __syncthreads();
    for (int i = tid; i < cn; i += BLK) {
        unsigned lo = lop[i];
        unsigned short eh = ewp[i];
        int p = atomicAdd(&pos[lo >> 17], 1);
        csr[base + p] = (lo & 0x1FFFF) | ((unsigned)(eh & 0x7FFF) << 17);
    }
}

__device__ __forceinline__ void accum4(float* acc, uint2 pk, float w) {
    float2 f0 = __half22float2(*(__half2*)&pk.x);
    float2 f1 = __half22float2(*(__half2*)&pk.y);
    acc[0] = fmaf(w, f0.x, acc[0]); acc[1] = fmaf(w, f0.y, acc[1]);
    acc[2] = fmaf(w, f1.x, acc[2]); acc[3] = fmaf(w, f1.y, acc[3]);
}
__device__ __forceinline__ float dec_w(unsigned e) {
    return __half2float(__ushort_as_half((unsigned short)(e >> 17)));
}

// Channel-quarter aggregate pass: tq = [node][16] fp16 (3.2MB, fits 4MB XCD L2).
// Wave: g=lane>>2 (16 edge slots), c4=lane&3 (4ch per lane). cn multiple of 16.
// csr via nontemporal loads, h via nontemporal stores -> L2 reserved for tq.
constexpr int AGG_GRID = 2048;
__global__ __launch_bounds__(BLK) void aggregate_bn(
    const __half* __restrict__ tq, const int* __restrict__ offs2,
    const int* __restrict__ cntg, const unsigned* __restrict__ csr,
    const float* __restrict__ bias, float* __restrict__ h,
    float* __restrict__ stats, int q, int n)
{
    int tid = threadIdx.x, lane = tid & 63, wid = tid >> 6;
    int g = lane >> 2, c4 = lane & 3;
    int ch0 = q * 16 + c4 * 4;
    int gwave = blockIdx.x * 4 + wid;
    int nwaves = gridDim.x * 4;
    float4 bb = *(const float4*)(bias + ch0);
    float bs[4] = {0.f, 0.f, 0.f, 0.f}, bs2[4] = {0.f, 0.f, 0.f, 0.f};
    const __half* tp = tq + c4 * 4;

    for (int node = gwave; node < n; node += nwaves) {
        int s0 = offs2[node] + g, cn = cntg[node];
        float acc[4] = {0.f, 0.f, 0.f, 0.f};
        int base = 0;
        for (; base + 32 <= cn; base += 32) {
            unsigned e0 = __builtin_nontemporal_load(csr + s0 + base);
            unsigned e1 = __builtin_nontemporal_load(csr + s0 + base + 16);
            uint2 p0 = *(const uint2*)(tp + (size_t)(e0 & 0x1FFFF) * 16);
            uint2 p1 = *(const uint2*)(tp + (size_t)(e1 & 0x1FFFF) * 16);
            accum4(acc, p0, dec_w(e0));
            accum4(acc, p1, dec_w(e1));
        }
        for (; base < cn; base += 16) {
            unsigned e0 = __builtin_nontemporal_load(csr + s0 + base);
            uint2 p0 = *(const uint2*)(tp + (size_t)(e0 & 0x1FFFF) * 16);
            accum4(acc, p0, dec_w(e0));
        }
#pragma unroll
        for (int d = 4; d < 64; d <<= 1) {
#pragma unroll
            for (int j = 0; j < 4; ++j) acc[j] += __shfl_xor(acc[j], d, 64);
        }
        if (g == 0) {
            float v0 = fmaxf(acc[0] + bb.x, 0.f);
            float v1 = fmaxf(acc[1] + bb.y, 0.f);
            float v2 = fmaxf(acc[2] + bb.z, 0.f);
            float v3 = fmaxf(acc[3] + bb.w, 0.f);
            unsigned long long u0 = ((unsigned long long)__float_as_uint(v1) << 32) | __float_as_uint(v0);
            unsigned long long u1 = ((unsigned long long)__float_as_uint(v3) << 32) | __float_as_uint(v2);
            unsigned long long* hp = (unsigned long long*)(h + (size_t)node * HID + ch0);
            __builtin_nontemporal_store(u0, hp);
            __builtin_nontemporal_store(u1, hp + 1);
            bs[0] += v0; bs2[0] += v0 * v0;
            bs[1] += v1; bs2[1] += v1 * v1;
            bs[2] += v2; bs2[2] += v2 * v2;
            bs[3] += v3; bs2[3] += v3 * v3;
        }
    }
    __shared__ float r1[4][16], r2[4][16];
    if (g == 0) {
#pragma unroll
        for (int j = 0; j < 4; ++j) {
            r1[wid][c4 * 4 + j] = bs[j];
            r2[wid][c4 * 4 + j] = bs2[j];
        }
    }
    __syncthreads();
    if (tid < 16) {
        float a = r1[0][tid] + r1[1][tid] + r1[2][tid] + r1[3][tid];
        float b = r2[0][tid] + r2[1][tid] + r2[2][tid] + r2[3][tid];
        atomicAdd(&stats[q * 16 + tid], a);
        atomicAdd(&stats[64 + q * 16 + tid], b);
    }
}

__global__ void bn_finalize(const float* __restrict__ stats, const float* __restrict__ g,
                            const float* __restrict__ be, float* __restrict__ scsh, float n) {
    int c = threadIdx.x;
    if (c < 64) {
        float mean = stats[c] / n;
        float var = stats[64 + c] / n - mean * mean;
        float s = 1.0f / sqrtf(var + 1e-5f);
        float sc = g[c] * s;
        scsh[c] = sc;
        scsh[64 + c] = be[c] - mean * sc;
    }
}

// T stored as 4 channel-quarters: T + q*N*16 + r*16. One thread per row, W in LDS.
template <int IN, int OUT, bool TRANS>
__global__ __launch_bounds__(BLK) void mm_kernel(
    const float* __restrict__ X, const float* __restrict__ W,
    const float* __restrict__ scale, const float* __restrict__ shift,
    __half* __restrict__ T, int n)
{
    __shared__ float Wl[IN * OUT];
    for (int i = threadIdx.x; i < IN * OUT; i += BLK) Wl[i] = W[i];
    __shared__ float sc[IN], sh[IN];
    if (TRANS) {
        for (int i = threadIdx.x; i < IN; i += BLK) {
            sc[i] = scale[i];
            sh[i] = shift[i];
        }
    }
    __syncthreads();
    int r = blockIdx.x * BLK + threadIdx.x;
    if (r >= n) return;
    float acc[OUT];
#pragma unroll
    for (int j = 0; j < OUT; ++j) acc[j] = 0.f;
    const float4* x4 = reinterpret_cast<const float4*>(X + (size_t)r * IN);
#pragma unroll 2
    for (int k4 = 0; k4 < IN / 4; ++k4) {
        float4 xv = x4[k4];
        float xs[4] = {xv.x, xv.y, xv.z, xv.w};
#pragma unroll
        for (int u = 0; u < 4; ++u) {
            int k = k4 * 4 + u;
            float xk = xs[u];
            if (TRANS) xk = xk * sc[k] + sh[k];
#pragma unroll
            for (int j = 0; j < OUT; ++j) acc[j] += xk * Wl[k * OUT + j];
        }
    }
    unsigned short tmp[OUT];
#pragma unroll
    for (int j = 0; j < OUT; ++j) tmp[j] = __half_as_ushort(__float2half_rn(acc[j]));
#pragma unroll
    for (int qq = 0; qq < OUT / 16; ++qq) {
        int4* dq = (int4*)(T + (size_t)qq * N_NODES * 16 + (size_t)r * 16);
        dq[0] = ((int4*)tmp)[qq * 2];
        dq[1] = ((int4*)tmp)[qq * 2 + 1];
    }
}

__device__ __forceinline__ float gelu_f(float v) {
    return 0.5f * v * (1.0f + erff(v * 0.70710678118654752f));
}

// Thread per row; W1 half-column packed as half2-over-k in LDS (8KB).
// Inner: v_dot2_f32_f16 (fp32 accumulate). Column half per blockIdx.y.
__global__ __launch_bounds__(BLK) void mlp1(
    const float* __restrict__ X, const float* __restrict__ W1,
    const float* __restrict__ B1, const float* __restrict__ scsh,
    __half* __restrict__ HB, int n)
{
    __shared__ unsigned Wl[32 * 64];   // [k2][j]
    __shared__ float sc[64], sh[64], bl[64];
    int half_ = blockIdx.y;
    for (int i = threadIdx.x; i < 32 * 64; i += BLK) {
        int k2 = i >> 6, j = i & 63;
        float a = W1[(2 * k2) * 128 + half_ * 64 + j];
        float b = W1[(2 * k2 + 1) * 128 + half_ * 64 + j];
        Wl[i] = __builtin_bit_cast(unsigned, __builtin_amdgcn_cvt_pkrtz(a, b));
    }
    if (threadIdx.x < 64) {
        sc[threadIdx.x] = scsh[threadIdx.x];
        sh[threadIdx.x] = scsh[64 + threadIdx.x];
        bl[threadIdx.x] = B1[half_ * 64 + threadIdx.x];
    }
    __syncthreads();
    int r = blockIdx.x * BLK + threadIdx.x;
    if (r >= n) return;
    unsigned xp[32];
    const float4* x4 = reinterpret_cast<const float4*>(X + (size_t)r * 64);
#pragma unroll
    for (int q = 0; q < 16; ++q) {
        float4 xv = x4[q];
        int k = q * 4;
        float a0 = xv.x * sc[k] + sh[k];
        float a1 = xv.y * sc[k + 1] + sh[k + 1];
        float a2 = xv.z * sc[k + 2] + sh[k + 2];
        float a3 = xv.w * sc[k + 3] + sh[k + 3];
        xp[q * 2]     = __builtin_bit_cast(unsigned, __builtin_amdgcn_cvt_pkrtz(a0, a1));
        xp[q * 2 + 1] = __builtin_bit_cast(unsigned, __builtin_amdgcn_cvt_pkrtz(a2, a3));
    }
    float acc[64];
#pragma unroll
    for (int j = 0; j < 64; ++j) acc[j] = bl[j];
#pragma unroll 4
    for (int k2 = 0; k2 < 32; ++k2) {
        unsigned xv = xp[k2];
#pragma unroll
        for (int j = 0; j < 64; ++j) acc[j] = fdot2(xv, Wl[k2 * 64 + j], acc[j]);
    }
    unsigned short tmp[64];
#pragma unroll
    for (int j = 0; j < 64; ++j)
        tmp[j] = __half_as_ushort(__float2half_rn(gelu_f(acc[j])));
    int4* dst4 = (int4*)(HB + (size_t)r * 128 + half_ * 64);
#pragma unroll
    for (int q = 0; q < 8; ++q) dst4[q] = ((int4*)tmp)[q];
}

// Thread per row; W2 packed half2-over-k in LDS (16KB); hb is half2 pairs.
__global__ __launch_bounds__(BLK) void mlp2(
    const __half* __restrict__ HB, const float* __restrict__ W2,
    const float* __restrict__ B2, const float* __restrict__ W3,
    const float* __restrict__ B3, float* __restrict__ Y, int n)
{
    __shared__ unsigned Wl[64 * 64];   // [k2][j]
    __shared__ float W3l[64 * 5];
    __shared__ float b2l[64], b3l[8];
    for (int i = threadIdx.x; i < 64 * 64; i += BLK) {
        int k2 = i >> 6, j = i & 63;
        float a = W2[(2 * k2) * 64 + j];
        float b = W2[(2 * k2 + 1) * 64 + j];
        Wl[i] = __builtin_bit_cast(unsigned, __builtin_amdgcn_cvt_pkrtz(a, b));
    }
    for (int i = threadIdx.x; i < 64 * 5; i += BLK) W3l[i] = W3[i];
    if (threadIdx.x < 64) b2l[threadIdx.x] = B2[threadIdx.x];
    if (threadIdx.x < 5) b3l[threadIdx.x] = B3[threadIdx.x];
    __syncthreads();
    int r = blockIdx.x * BLK + threadIdx.x;
    if (r >= n) return;
    float acc[64];
#pragma unroll
    for (int j = 0; j < 64; ++j) acc[j] = b2l[j];
    const uint4* x4 = reinterpret_cast<const uint4*>(HB + (size_t)r * 128);
#pragma unroll 2
    for (int q = 0; q < 16; ++q) {
        uint4 pk = x4[q];
        unsigned xs[4] = {pk.x, pk.y, pk.z, pk.w};
#pragma unroll
        for (int u = 0; u < 4; ++u) {
            int k2 = q * 4 + u;
            unsigned xv = xs[u];
#pragma unroll
            for (int j = 0; j < 64; ++j) acc[j] = fdot2(xv, Wl[k2 * 64 + j], acc[j]);
        }
    }
    float o[5];
#pragma unroll
    for (int j = 0; j < 5; ++j) o[j] = b3l[j];
#pragma unroll
    for (int k = 0; k < 64; ++k) {
        float g = gelu_f(acc[k]);
#pragma unroll
        for (int j = 0; j < 5; ++j) o[j] += g * W3l[k * 5 + j];
    }
    float* yr = Y + (size_t)r * 5;
#pragma unroll
    for (int j = 0; j < 5; ++j) yr[j] = o[j];
}

extern "C" void kernel_launch(void* const* d_in, const int* in_sizes, int n_in,
                              void* d_out, int out_size, void* d_ws, size_t ws_size,
                              hipStream_t stream)
{
    const float* x   = (const float*)d_in[0];
    const int*   ei  = (const int*)d_in[1];
    const int*   srcs = ei;
    const int*   dsts = ei + N_EDGES;
    const float* ew  = (const float*)d_in[2];
    const float* cw0 = (const float*)d_in[3];  const float* cb0 = (const float*)d_in[4];
    const float* cw1 = (const float*)d_in[5];  const float* cb1 = (const float*)d_in[6];
    const float* cw2 = (const float*)d_in[7];  const float* cb2 = (const float*)d_in[8];
    const float* g0  = (const float*)d_in[9];  const float* be0 = (const float*)d_in[10];
    const float* g1  = (const float*)d_in[11]; const float* be1 = (const float*)d_in[12];
    const float* g2  = (const float*)d_in[13]; const float* be2 = (const float*)d_in[14];
    const float* mw1 = (const float*)d_in[15]; const float* mb1 = (const float*)d_in[16];
    const float* mw2 = (const float*)d_in[17]; const float* mb2 = (const float*)d_in[18];
    const float* mw3 = (const float*)d_in[19]; const float* mb3 = (const float*)d_in[20];
    float* out = (float*)d_out;

    char* ws = (char*)d_ws;
    size_t off = 0;
    auto alloc = [&](size_t b) { size_t o = off; off = (off + b + 511) & ~(size_t)511; return o; };

    int*   cursor     = (int*)(ws + alloc((size_t)NBUCK * 4));
    float* stats      = (float*)(ws + alloc(3 * 128 * 4));
    float* scsh       = (float*)(ws + alloc(3 * 128 * 4));
    int*   offs2      = (int*)(ws + alloc((size_t)N_NODES * 4));
    int*   cntg       = (int*)(ws + alloc((size_t)N_NODES * 4));
    size_t o_csr      = alloc((size_t)NBUCK * CAPP * 4);               // 20.4 MB
    unsigned* csr     = (unsigned*)(ws + o_csr);
    size_t o_t        = alloc((size_t)N_NODES * HID * 2);              // 12.8 MB (4 quarters)
    __half* t         = (__half*)(ws + o_t);
    float* h          = (float*)(ws + alloc((size_t)N_NODES * HID * 4)); // 25.6 MB
    // ebuf SoA (14.4 + 7.2 MB) aliases t+h (38.4 MB): dead before t/h first written
    unsigned*       ebuf_lo = (unsigned*)(ws + o_t);
    unsigned short* ebuf_ew = (unsigned short*)(ws + o_t + (size_t)NBUCK * CAP * 4);
    // hb fp16 (25.6 MB) aliases csr+t (33.2 MB): both dead after the last aggregate
    __half* hb        = (__half*)(ws + o_csr);

    // ---- chunk-sorted edge scatter -> padded packed dst-CSR (once per call) ----
    init_k<<<(NBUCK + 384 + BLK - 1) / BLK, BLK, 0, stream>>>(cursor, stats);
    sort_scatter<<<NCHUNK, BLK, 0, stream>>>(srcs, dsts, ew, cursor, ebuf_lo, ebuf_ew);
    build_csr<<<NBUCK, BLK, 0, stream>>>(ebuf_lo, ebuf_ew, cursor, offs2, cntg, csr);

    // ---- Layer 0 ----
    mm_kernel<INC, HID, false><<<NBLK_N, BLK, 0, stream>>>(x, cw0, nullptr, nullptr, t, N_NODES);
    for (int q = 0; q < 4; ++q)
        aggregate_bn<<<AGG_GRID, BLK, 0, stream>>>(t + (size_t)q * N_NODES * 16, offs2, cntg, csr, cb0, h, stats, q, N_NODES);
    bn_finalize<<<1, 64, 0, stream>>>(stats, g0, be0, scsh, (float)N_NODES);

    // ---- Layer 1 ----
    mm_kernel<HID, HID, true><<<NBLK_N, BLK, 0, stream>>>(h, cw1, scsh, scsh + 64, t, N_NODES);
    for (int q = 0; q < 4; ++q)
        aggregate_bn<<<AGG_GRID, BLK, 0, stream>>>(t + (size_t)q * N_NODES * 16, offs2, cntg, csr, cb1, h, stats + 128, q, N_NODES);
    bn_finalize<<<1, 64, 0, stream>>>(stats + 128, g1, be1, scsh + 128, (float)N_NODES);

    // ---- Layer 2 ----
    mm_kernel<HID, HID, true><<<NBLK_N, BLK, 0, stream>>>(h, cw2, scsh + 128, scsh + 192, t, N_NODES);
    for (int q = 0; q < 4; ++q)
        aggregate_bn<<<AGG_GRID, BLK, 0, stream>>>(t + (size_t)q * N_NODES * 16, offs2, cntg, csr, cb2, h, stats + 256, q, N_NODES);
    bn_finalize<<<1, 64, 0, stream>>>(stats + 256, g2, be2, scsh + 256, (float)N_NODES);

    // ---- MLP (thread-per-row, fp16 packed weights, v_dot2_f32_f16) ----
    mlp1<<<dim3(NBLK_N, 2), BLK, 0, stream>>>(h, mw1, mb1, scsh + 256, hb, N_NODES);
    mlp2<<<NBLK_N, BLK, 0, stream>>>(hb, mw2, mb2, mw3, mb3, out, N_NODES);
}

// Round 14
// 555.543 us; speedup vs baseline: 1.7493x; 1.7493x over previous
//
#include <hip/hip_runtime.h>
#include <hip/hip_fp16.h>
#include <math.h>

#define N_NODES 100000
#define N_EDGES 3200000
#define INC 128
#define HID 64

constexpr int BLK = 256;
constexpr int NBLK_N = (N_NODES + BLK - 1) / BLK;   // 391

constexpr int NBUCK = (N_NODES + 127) / 128;        // 782 buckets of 128 dsts
constexpr int CAP = 4608;                           // staging cap: mean 4096 + 8 sigma
constexpr int CAPP = 5632;                          // csr region cap (pad-8 headroom)
constexpr int CHUNK = 8192;
constexpr int NCHUNK = (N_EDGES + CHUNK - 1) / CHUNK; // 391

typedef _Float16 half2v __attribute__((ext_vector_type(2)));
__device__ __forceinline__ float fdot2(unsigned a, unsigned b, float c) {
    return __builtin_amdgcn_fdot2(__builtin_bit_cast(half2v, a),
                                  __builtin_bit_cast(half2v, b), c, false);
}

__global__ void init_k(int* __restrict__ cursor, float* __restrict__ stats) {
    int i = blockIdx.x * blockDim.x + threadIdx.x;
    if (i < NBUCK) cursor[i] = i * CAP;
    else if (i < NBUCK + 384) stats[i - NBUCK] = 0.f;
}

// One block per 8192-edge chunk: bucket-sort in LDS, one global atomic per
// non-empty bucket, coalesced SoA flush (4B+2B).
__global__ __launch_bounds__(BLK) void sort_scatter(
    const int* __restrict__ src, const int* __restrict__ dst,
    const float* __restrict__ ew, int* __restrict__ gcur,
    unsigned* __restrict__ ebuf_lo, unsigned short* __restrict__ ebuf_ew)
{
    __shared__ unsigned s_lo[CHUNK];
    __shared__ unsigned short s_ew[CHUNK];
    __shared__ int s_cnt[NBUCK];
    __shared__ int s_base[NBUCK];
    int tid = threadIdx.x;
    int c0 = blockIdx.x * CHUNK;
    int T = min(CHUNK, N_EDGES - c0);
    if (T <= 0) return;
    for (int i = tid; i < NBUCK; i += BLK) s_cnt[i] = 0;
    __syncthreads();
    for (int i = tid; i < T; i += BLK)
        atomicAdd(&s_cnt[dst[c0 + i] >> 7], 1);
    __syncthreads();
    int* a = (int*)s_lo;
    int* b2 = a + 1024;
    for (int i = tid; i < NBUCK; i += BLK) a[i] = s_cnt[i];
    __syncthreads();
    for (int d = 1; d < NBUCK; d <<= 1) {
        for (int i = tid; i < NBUCK; i += BLK) b2[i] = a[i] + (i >= d ? a[i - d] : 0);
        __syncthreads();
        int* tmp = a; a = b2; b2 = tmp;
    }
    for (int b = tid; b < NBUCK; b += BLK) {
        int cnt = s_cnt[b];
        int pex = a[b] - cnt;
        int gb = cnt ? (atomicAdd(&gcur[b], cnt) - b * CAP) : 0;
        s_base[b] = gb - pex;
        s_cnt[b] = pex;
    }
    __syncthreads();
    for (int i = tid; i < T; i += BLK) {
        int d = dst[c0 + i];
        int s = src[c0 + i];
        float w = ew[c0 + i];
        int b = d >> 7;
        int r = atomicAdd(&s_cnt[b], 1);
        s_lo[r] = (unsigned)s | ((unsigned)(d & 127) << 17);
        s_ew[r] = __half_as_ushort(__float2half_rn(w));
    }
    __syncthreads();
    for (int j = tid; j < T; j += BLK) {
        int lo = 0, hi = NBUCK - 1;
        while (lo < hi) { int mid = (lo + hi) >> 1; if (s_cnt[mid] > j) hi = mid; else lo = mid + 1; }
        int b = lo;
        int rel = s_base[b] + j;
        if (rel < CAP) {
            ebuf_lo[(size_t)b * CAP + rel] = s_lo[j];
            ebuf_ew[(size_t)b * CAP + rel] = s_ew[j];
        }
    }
}

// One block per bucket: per-dst counts, padded (x8) scan, dst-sorted rewrite into
// fixed region [b*CAPP...]. Entry 4B: src(17b) | fp16-ew-no-sign(15b).
__global__ __launch_bounds__(BLK) void build_csr(
    const unsigned* __restrict__ ebuf_lo, const unsigned short* __restrict__ ebuf_ew,
    const int* __restrict__ gcur, int* __restrict__ offs2,
    int* __restrict__ cntg, unsigned* __restrict__ csr)
{
    __shared__ int cntl[128];
    __shared__ int scp[128];
    __shared__ int pos[128];
    int b = blockIdx.x, tid = threadIdx.x;
    if (tid < 128) cntl[tid] = 0;
    __syncthreads();
    int cn = min(gcur[b] - b * CAP, CAP);
    const unsigned* lop = ebuf_lo + (size_t)b * CAP;
    const unsigned short* ewp = ebuf_ew + (size_t)b * CAP;
    for (int i = tid; i < cn; i += BLK)
        atomicAdd(&cntl[lop[i] >> 17], 1);
    __syncthreads();
    if (tid < 128) scp[tid] = (cntl[tid] + 7) & ~7;
    __syncthreads();
    for (int d = 1; d < 128; d <<= 1) {
        int t = (tid < 128 && tid >= d) ? scp[tid - d] : 0;
        __syncthreads();
        if (tid < 128) scp[tid] += t;
        __syncthreads();
    }
    int base = b * CAPP;
    int node0 = b * 128;
    if (tid < 128) {
        int cnt = cntl[tid];
        int cp = (cnt + 7) & ~7;
        int excl = scp[tid] - cp;
        pos[tid] = excl;
        if (node0 + tid < N_NODES) {
            offs2[node0 + tid] = base + excl;
            cntg[node0 + tid] = cp;
        }
        for (int q = cnt; q < cp; ++q) csr[base + excl + q] = 0u;  // w=0 pad
    }
    __syncthreads();
    for (int i = tid; i < cn; i += BLK) {
        unsigned lo = lop[i];
        unsigned short eh = ewp[i];
        int p = atomicAdd(&pos[lo >> 17], 1);
        csr[base + p] = (lo & 0x1FFFF) | ((unsigned)(eh & 0x7FFF) << 17);
    }
}

__device__ __forceinline__ void accum8(float* acc, const uint4& pk, float w) {
    const __half2* hp = (const __half2*)&pk;
    float2 f0 = __half22float2(hp[0]);
    float2 f1 = __half22float2(hp[1]);
    float2 f2 = __half22float2(hp[2]);
    float2 f3 = __half22float2(hp[3]);
    acc[0] = fmaf(w, f0.x, acc[0]); acc[1] = fmaf(w, f0.y, acc[1]);
    acc[2] = fmaf(w, f1.x, acc[2]); acc[3] = fmaf(w, f1.y, acc[3]);
    acc[4] = fmaf(w, f2.x, acc[4]); acc[5] = fmaf(w, f2.y, acc[5]);
    acc[6] = fmaf(w, f3.x, acc[6]); acc[7] = fmaf(w, f3.y, acc[7]);
}
__device__ __forceinline__ float dec_w(unsigned e) {
    return __half2float(__ushort_as_half((unsigned short)(e >> 17)));
}

// Wave per dst node (round-10 form: pad-8, 4x unroll, low VGPR -> ~47% occ).
constexpr int AGG_GRID = 2048;
__global__ __launch_bounds__(BLK) void aggregate_bn(
    const __half* __restrict__ t, const int* __restrict__ offs2,
    const int* __restrict__ cntg, const unsigned* __restrict__ csr,
    const float* __restrict__ bias, float* __restrict__ h,
    float* __restrict__ stats, int n)
{
    int tid = threadIdx.x, lane = tid & 63, wid = tid >> 6;
    int g = lane >> 3, c8 = lane & 7;
    int gwave = blockIdx.x * 4 + wid;
    int nwaves = gridDim.x * 4;
    float4 bb0 = *(const float4*)(bias + c8 * 8);
    float4 bb1 = *(const float4*)(bias + c8 * 8 + 4);
    float bs[8], bs2[8];
#pragma unroll
    for (int j = 0; j < 8; ++j) { bs[j] = 0.f; bs2[j] = 0.f; }

    for (int node = gwave; node < n; node += nwaves) {
        int s0 = offs2[node] + g, cn = cntg[node];
        float acc[8];
#pragma unroll
        for (int j = 0; j < 8; ++j) acc[j] = 0.f;
        const __half* tp = t + c8 * 8;
        int base = 0;
        for (; base + 32 <= cn; base += 32) {
            unsigned e0 = csr[s0 + base];
            unsigned e1 = csr[s0 + base + 8];
            unsigned e2 = csr[s0 + base + 16];
            unsigned e3 = csr[s0 + base + 24];
            uint4 p0 = *(const uint4*)(tp + (size_t)(e0 & 0x1FFFF) * HID);
            uint4 p1 = *(const uint4*)(tp + (size_t)(e1 & 0x1FFFF) * HID);
            uint4 p2 = *(const uint4*)(tp + (size_t)(e2 & 0x1FFFF) * HID);
            uint4 p3 = *(const uint4*)(tp + (size_t)(e3 & 0x1FFFF) * HID);
            accum8(acc, p0, dec_w(e0));
            accum8(acc, p1, dec_w(e1));
            accum8(acc, p2, dec_w(e2));
            accum8(acc, p3, dec_w(e3));
        }
        for (; base < cn; base += 8) {
            unsigned e0 = csr[s0 + base];
            uint4 p0 = *(const uint4*)(tp + (size_t)(e0 & 0x1FFFF) * HID);
            accum8(acc, p0, dec_w(e0));
        }
#pragma unroll
        for (int d = 8; d < 64; d <<= 1) {
#pragma unroll
            for (int j = 0; j < 8; ++j) acc[j] += __shfl_xor(acc[j], d, 64);
        }
        if (g == 0) {
            float v[8];
            v[0] = fmaxf(acc[0] + bb0.x, 0.f); v[1] = fmaxf(acc[1] + bb0.y, 0.f);
            v[2] = fmaxf(acc[2] + bb0.z, 0.f); v[3] = fmaxf(acc[3] + bb0.w, 0.f);
            v[4] = fmaxf(acc[4] + bb1.x, 0.f); v[5] = fmaxf(acc[5] + bb1.y, 0.f);
            v[6] = fmaxf(acc[6] + bb1.z, 0.f); v[7] = fmaxf(acc[7] + bb1.w, 0.f);
            float* hr = h + (size_t)node * HID + c8 * 8;
            *(float4*)hr = float4{v[0], v[1], v[2], v[3]};
            *(float4*)(hr + 4) = float4{v[4], v[5], v[6], v[7]};
#pragma unroll
            for (int j = 0; j < 8; ++j) { bs[j] += v[j]; bs2[j] += v[j] * v[j]; }
        }
    }
    __shared__ float r1[4][64], r2[4][64];
    if (g == 0) {
#pragma unroll
        for (int j = 0; j < 8; ++j) {
            r1[wid][c8 * 8 + j] = bs[j];
            r2[wid][c8 * 8 + j] = bs2[j];
        }
    }
    __syncthreads();
    if (tid < 64) {
        atomicAdd(&stats[tid], r1[0][tid] + r1[1][tid] + r1[2][tid] + r1[3][tid]);
        atomicAdd(&stats[64 + tid], r2[0][tid] + r2[1][tid] + r2[2][tid] + r2[3][tid]);
    }
}

__global__ void bn_finalize(const float* __restrict__ stats, const float* __restrict__ g,
                            const float* __restrict__ be, float* __restrict__ scsh, float n) {
    int c = threadIdx.x;
    if (c < 64) {
        float mean = stats[c] / n;
        float var = stats[64 + c] / n - mean * mean;
        float s = 1.0f / sqrtf(var + 1e-5f);
        float sc = g[c] * s;
        scsh[c] = sc;
        scsh[64 + c] = be[c] - mean * sc;
    }
}

// T[r,:] = half((trans? X*sc+sh : X)[r,:] @ W); one thread per row, W in LDS.
template <int IN, int OUT, bool TRANS>
__global__ __launch_bounds__(BLK) void mm_kernel(
    const float* __restrict__ X, const float* __restrict__ W,
    const float* __restrict__ scale, const float* __restrict__ shift,
    __half* __restrict__ T, int n)
{
    __shared__ float Wl[IN * OUT];
    for (int i = threadIdx.x; i < IN * OUT; i += BLK) Wl[i] = W[i];
    __shared__ float sc[IN], sh[IN];
    if (TRANS) {
        for (int i = threadIdx.x; i < IN; i += BLK) {
            sc[i] = scale[i];
            sh[i] = shift[i];
        }
    }
    __syncthreads();
    int r = blockIdx.x * BLK + threadIdx.x;
    if (r >= n) return;
    float acc[OUT];
#pragma unroll
    for (int j = 0; j < OUT; ++j) acc[j] = 0.f;
    const float4* x4 = reinterpret_cast<const float4*>(X + (size_t)r * IN);
#pragma unroll 2
    for (int k4 = 0; k4 < IN / 4; ++k4) {
        float4 xv = x4[k4];
        float xs[4] = {xv.x, xv.y, xv.z, xv.w};
#pragma unroll
        for (int u = 0; u < 4; ++u) {
            int k = k4 * 4 + u;
            float xk = xs[u];
            if (TRANS) xk = xk * sc[k] + sh[k];
#pragma unroll
            for (int j = 0; j < OUT; ++j) acc[j] += xk * Wl[k * OUT + j];
        }
    }
    unsigned short tmp[OUT];
#pragma unroll
    for (int j = 0; j < OUT; ++j) tmp[j] = __half_as_ushort(__float2half_rn(acc[j]));
    int4* dst4 = (int4*)(T + (size_t)r * OUT);
#pragma unroll
    for (int q = 0; q < OUT / 8; ++q) dst4[q] = ((int4*)tmp)[q];
}

__device__ __forceinline__ float gelu_f(float v) {
    return 0.5f * v * (1.0f + erff(v * 0.70710678118654752f));
}

// Thread per row, column-QUARTER per blockIdx.y (32 outputs/thread -> low VGPR,
// high occupancy). W1 quarter packed half2-over-k in LDS (4KB). fdot2 inner.
__global__ __launch_bounds__(BLK) void mlp1(
    const float* __restrict__ X, const float* __restrict__ W1,
    const float* __restrict__ B1, const float* __restrict__ scsh,
    __half* __restrict__ HB, int n)
{
    __shared__ unsigned Wl[32 * 32];   // [k2][j]
    __shared__ float sc[64], sh[64], bl[32];
    int qt = blockIdx.y;               // 0..3
    for (int i = threadIdx.x; i < 32 * 32; i += BLK) {
        int k2 = i >> 5, j = i & 31;
        float a = W1[(2 * k2) * 128 + qt * 32 + j];
        float b = W1[(2 * k2 + 1) * 128 + qt * 32 + j];
        Wl[i] = __builtin_bit_cast(unsigned, __builtin_amdgcn_cvt_pkrtz(a, b));
    }
    if (threadIdx.x < 64) {
        sc[threadIdx.x] = scsh[threadIdx.x];
        sh[threadIdx.x] = scsh[64 + threadIdx.x];
    }
    if (threadIdx.x < 32) bl[threadIdx.x] = B1[qt * 32 + threadIdx.x];
    __syncthreads();
    int r = blockIdx.x * BLK + threadIdx.x;
    if (r >= n) return;
    unsigned xp[32];
    const float4* x4 = reinterpret_cast<const float4*>(X + (size_t)r * 64);
#pragma unroll
    for (int q = 0; q < 16; ++q) {
        float4 xv = x4[q];
        int k = q * 4;
        float a0 = xv.x * sc[k] + sh[k];
        float a1 = xv.y * sc[k + 1] + sh[k + 1];
        float a2 = xv.z * sc[k + 2] + sh[k + 2];
        float a3 = xv.w * sc[k + 3] + sh[k + 3];
        xp[q * 2]     = __builtin_bit_cast(unsigned, __builtin_amdgcn_cvt_pkrtz(a0, a1));
        xp[q * 2 + 1] = __builtin_bit_cast(unsigned, __builtin_amdgcn_cvt_pkrtz(a2, a3));
    }
    float acc[32];
#pragma unroll
    for (int j = 0; j < 32; ++j) acc[j] = bl[j];
#pragma unroll 4
    for (int k2 = 0; k2 < 32; ++k2) {
        unsigned xv = xp[k2];
#pragma unroll
        for (int j = 0; j < 32; ++j) acc[j] = fdot2(xv, Wl[k2 * 32 + j], acc[j]);
    }
    unsigned short tmp[32];
#pragma unroll
    for (int j = 0; j < 32; ++j)
        tmp[j] = __half_as_ushort(__float2half_rn(gelu_f(acc[j])));
    int4* dst4 = (int4*)(HB + (size_t)r * 128 + qt * 32);
#pragma unroll
    for (int q = 0; q < 4; ++q) dst4[q] = ((int4*)tmp)[q];
}

// Thread per row; W2 packed half2-over-k in LDS (16KB); hb is half2 pairs.
__global__ __launch_bounds__(BLK) void mlp2(
    const __half* __restrict__ HB, const float* __restrict__ W2,
    const float* __restrict__ B2, const float* __restrict__ W3,
    const float* __restrict__ B3, float* __restrict__ Y, int n)
{
    __shared__ unsigned Wl[64 * 64];   // [k2][j]
    __shared__ float W3l[64 * 5];
    __shared__ float b2l[64], b3l[8];
    for (int i = threadIdx.x; i < 64 * 64; i += BLK) {
        int k2 = i >> 6, j = i & 63;
        float a = W2[(2 * k2) * 64 + j];
        float b = W2[(2 * k2 + 1) * 64 + j];
        Wl[i] = __builtin_bit_cast(unsigned, __builtin_amdgcn_cvt_pkrtz(a, b));
    }
    for (int i = threadIdx.x; i < 64 * 5; i += BLK) W3l[i] = W3[i];
    if (threadIdx.x < 64) b2l[threadIdx.x] = B2[threadIdx.x];
    if (threadIdx.x < 5) b3l[threadIdx.x] = B3[threadIdx.x];
    __syncthreads();
    int r = blockIdx.x * BLK + threadIdx.x;
    if (r >= n) return;
    float acc[64];
#pragma unroll
    for (int j = 0; j < 64; ++j) acc[j] = b2l[j];
    const uint4* x4 = reinterpret_cast<const uint4*>(HB + (size_t)r * 128);
#pragma unroll 2
    for (int q = 0; q < 16; ++q) {
        uint4 pk = x4[q];
        unsigned xs[4] = {pk.x, pk.y, pk.z, pk.w};
#pragma unroll
        for (int u = 0; u < 4; ++u) {
            int k2 = q * 4 + u;
            unsigned xv = xs[u];
#pragma unroll
            for (int j = 0; j < 64; ++j) acc[j] = fdot2(xv, Wl[k2 * 64 + j], acc[j]);
        }
    }
    float o[5];
#pragma unroll
    for (int j = 0; j < 5; ++j) o[j] = b3l[j];
#pragma unroll
    for (int k = 0; k < 64; ++k) {
        float g = gelu_f(acc[k]);
#pragma unroll
        for (int j = 0; j < 5; ++j) o[j] += g * W3l[k * 5 + j];
    }
    float* yr = Y + (size_t)r * 5;
#pragma unroll
    for (int j = 0; j < 5; ++j) yr[j] = o[j];
}

extern "C" void kernel_launch(void* const* d_in, const int* in_sizes, int n_in,
                              void* d_out, int out_size, void* d_ws, size_t ws_size,
                              hipStream_t stream)
{
    const float* x   = (const float*)d_in[0];
    const int*   ei  = (const int*)d_in[1];
    const int*   srcs = ei;
    const int*   dsts = ei + N_EDGES;
    const float* ew  = (const float*)d_in[2];
    const float* cw0 = (const float*)d_in[3];  const float* cb0 = (const float*)d_in[4];
    const float* cw1 = (const float*)d_in[5];  const float* cb1 = (const float*)d_in[6];
    const float* cw2 = (const float*)d_in[7];  const float* cb2 = (const float*)d_in[8];
    const float* g0  = (const float*)d_in[9];  const float* be0 = (const float*)d_in[10];
    const float* g1  = (const float*)d_in[11]; const float* be1 = (const float*)d_in[12];
    const float* g2  = (const float*)d_in[13]; const float* be2 = (const float*)d_in[14];
    const float* mw1 = (const float*)d_in[15]; const float* mb1 = (const float*)d_in[16];
    const float* mw2 = (const float*)d_in[17]; const float* mb2 = (const float*)d_in[18];
    const float* mw3 = (const float*)d_in[19]; const float* mb3 = (const float*)d_in[20];
    float* out = (float*)d_out;

    char* ws = (char*)d_ws;
    size_t off = 0;
    auto alloc = [&](size_t b) { size_t o = off; off = (off + b + 511) & ~(size_t)511; return o; };

    int*   cursor     = (int*)(ws + alloc((size_t)NBUCK * 4));
    float* stats      = (float*)(ws + alloc(3 * 128 * 4));
    float* scsh       = (float*)(ws + alloc(3 * 128 * 4));
    int*   offs2      = (int*)(ws + alloc((size_t)N_NODES * 4));
    int*   cntg       = (int*)(ws + alloc((size_t)N_NODES * 4));
    size_t o_csr      = alloc((size_t)NBUCK * CAPP * 4);               // 17.6 MB
    unsigned* csr     = (unsigned*)(ws + o_csr);
    size_t o_t        = alloc((size_t)N_NODES * HID * 2);              // 12.8 MB
    __half* t         = (__half*)(ws + o_t);
    float* h          = (float*)(ws + alloc((size_t)N_NODES * HID * 4)); // 25.6 MB
    // ebuf SoA (14.4 + 7.2 MB) aliases t+h (38.4 MB): dead before t/h first written
    unsigned*       ebuf_lo = (unsigned*)(ws + o_t);
    unsigned short* ebuf_ew = (unsigned short*)(ws + o_t + (size_t)NBUCK * CAP * 4);
    // hb fp16 (25.6 MB) aliases csr+t (30.4 MB): both dead after the last aggregate
    __half* hb        = (__half*)(ws + o_csr);

    // ---- chunk-sorted edge scatter -> padded packed dst-CSR (once per call) ----
    init_k<<<(NBUCK + 384 + BLK - 1) / BLK, BLK, 0, stream>>>(cursor, stats);
    sort_scatter<<<NCHUNK, BLK, 0, stream>>>(srcs, dsts, ew, cursor, ebuf_lo, ebuf_ew);
    build_csr<<<NBUCK, BLK, 0, stream>>>(ebuf_lo, ebuf_ew, cursor, offs2, cntg, csr);

    // ---- Layer 0 ----
    mm_kernel<INC, HID, false><<<NBLK_N, BLK, 0, stream>>>(x, cw0, nullptr, nullptr, t, N_NODES);
    aggregate_bn<<<AGG_GRID, BLK, 0, stream>>>(t, offs2, cntg, csr, cb0, h, stats, N_NODES);
    bn_finalize<<<1, 64, 0, stream>>>(stats, g0, be0, scsh, (float)N_NODES);

    // ---- Layer 1 ----
    mm_kernel<HID, HID, true><<<NBLK_N, BLK, 0, stream>>>(h, cw1, scsh, scsh + 64, t, N_NODES);
    aggregate_bn<<<AGG_GRID, BLK, 0, stream>>>(t, offs2, cntg, csr, cb1, h, stats + 128, N_NODES);
    bn_finalize<<<1, 64, 0, stream>>>(stats + 128, g1, be1, scsh + 128, (float)N_NODES);

    // ---- Layer 2 ----
    mm_kernel<HID, HID, true><<<NBLK_N, BLK, 0, stream>>>(h, cw2, scsh + 128, scsh + 192, t, N_NODES);
    aggregate_bn<<<AGG_GRID, BLK, 0, stream>>>(t, offs2, cntg, csr, cb2, h, stats + 256, N_NODES);
    bn_finalize<<<1, 64, 0, stream>>>(stats + 256, g2, be2, scsh + 256, (float)N_NODES);

    // ---- MLP (thread-per-row, fp16 packed weights, fdot2; mlp1 column-quartered) ----
    mlp1<<<dim3(NBLK_N, 4), BLK, 0, stream>>>(h, mw1, mb1, scsh + 256, hb, N_NODES);
    mlp2<<<NBLK_N, BLK, 0, stream>>>(hb, mw2, mb2, mw3, mb3, out, N_NODES);
}